// Round 19
// baseline (5285.038 us; speedup 1.0000x reference)
//
#include <hip/hip_runtime.h>

namespace {
constexpr int N_ROWS = 8192;
constexpr int N_E    = 16384;
constexpr int D      = 256;
constexpr int KC     = 512;   // BLIS/AOCL Zen4-5 sgemm KC (8192=16*512, 16384=32*512 exact)
}

// Pin the exact f32 value/rounding sequence: opaque register barrier.
#define PIN(x) asm volatile("" : "+v"(x))

// kbo: bo[j][k] = sum_n Ro[n][j]*X[n][k], k<8.
// kc=512 panels; within panel ONE f32 accumulator per element, ascending n,
// FMA; one f32 add to C per panel (BLIS macrokernel beta-update).
__global__ __launch_bounds__(64) void kbo(
    const float* __restrict__ Ro, const float* __restrict__ X,
    float* __restrict__ bo)
{
    const int j = blockIdx.x * 64 + threadIdx.x;

    float C[8];
    #pragma unroll
    for (int k = 0; k < 8; ++k) C[k] = 0.f;

    for (int p0 = 0; p0 < N_ROWS; p0 += KC) {
        float loc[8];
        #pragma unroll
        for (int k = 0; k < 8; ++k) loc[k] = 0.f;

        for (int t = 0; t < KC; t += 32) {
            #pragma unroll
            for (int u = 0; u < 32; ++u) {
                const int n = p0 + t + u;
                const float rv = Ro[(size_t)n * N_E + j];
                const float4 xa = *(const float4*)(X + (size_t)n * D);
                const float4 xb = *(const float4*)(X + (size_t)n * D + 4);
                loc[0] = fmaf(rv, xa.x, loc[0]); PIN(loc[0]);
                loc[1] = fmaf(rv, xa.y, loc[1]); PIN(loc[1]);
                loc[2] = fmaf(rv, xa.z, loc[2]); PIN(loc[2]);
                loc[3] = fmaf(rv, xa.w, loc[3]); PIN(loc[3]);
                loc[4] = fmaf(rv, xb.x, loc[4]); PIN(loc[4]);
                loc[5] = fmaf(rv, xb.y, loc[5]); PIN(loc[5]);
                loc[6] = fmaf(rv, xb.z, loc[6]); PIN(loc[6]);
                loc[7] = fmaf(rv, xb.w, loc[7]); PIN(loc[7]);
            }
        }
        #pragma unroll
        for (int k = 0; k < 8; ++k) { C[k] += loc[k]; PIN(C[k]); }  // one add/panel
    }
    #pragma unroll
    for (int k = 0; k < 8; ++k) bo[(size_t)j * 8 + k] = C[k];
}

// kmi: mi[i][k] = sum_j f32(Ri[i][j]*e[j]) * bo[j][k].
// kc=512 panels over j, single FMA chain per element within panel,
// one f32 add to C per panel; Rwi rounded once (materialized elementwise).
__global__ __launch_bounds__(256) void kmi(
    const float* __restrict__ Ri, const float* __restrict__ e,
    const float* __restrict__ bo, float* __restrict__ mi)
{
    const int tid = blockIdx.x * 256 + threadIdx.x;
    const int k   = tid & 7;
    const int i   = tid >> 3;
    const float* rrow = Ri + (size_t)i * N_E;

    float C = 0.f;
    for (int p0 = 0; p0 < N_E; p0 += KC) {
        float loc = 0.f;
        for (int t = 0; t < KC; t += 4) {
            const int j = p0 + t;
            const float4 rv = *(const float4*)(rrow + j);
            const float4 ev = *(const float4*)(e + j);
            float w0 = __fmul_rn(rv.x, ev.x); PIN(w0);
            float w1 = __fmul_rn(rv.y, ev.y); PIN(w1);
            float w2 = __fmul_rn(rv.z, ev.z); PIN(w2);
            float w3 = __fmul_rn(rv.w, ev.w); PIN(w3);
            loc = fmaf(w0, bo[(size_t)(j + 0) * 8 + k], loc); PIN(loc);
            loc = fmaf(w1, bo[(size_t)(j + 1) * 8 + k], loc); PIN(loc);
            loc = fmaf(w2, bo[(size_t)(j + 2) * 8 + k], loc); PIN(loc);
            loc = fmaf(w3, bo[(size_t)(j + 3) * 8 + k], loc); PIN(loc);
        }
        C += loc; PIN(C);                            // one rounded add / panel
    }
    mi[(size_t)i * 8 + k] = C;
}

// ---- circuit helpers (f64): amp index bits 0..5 = lane, bits 6..7 = reg ----
__device__ __forceinline__ void cnot_ll(double amp[4], int lane, int cmask, int tmask) {
    const bool c = (lane & cmask) != 0;
    #pragma unroll
    for (int r = 0; r < 4; ++r) {
        double p = __shfl_xor(amp[r], tmask);
        amp[r] = c ? p : amp[r];
    }
}
__device__ __forceinline__ void ry_lane(double amp[4], int lane, int bmask, double cc, double ss) {
    const bool b = (lane & bmask) != 0;
    #pragma unroll
    for (int r = 0; r < 4; ++r) {
        double p  = __shfl_xor(amp[r], bmask);
        double sp = ss * p;
        amp[r] = fma(cc, amp[r], b ? sp : -sp);
    }
}

// kcirc: quantum circuit (f64) from f32 mi angles, 4 rows per wave
__global__ __launch_bounds__(256) void kcirc(
    const float* __restrict__ mi, const float* __restrict__ theta,
    float* __restrict__ out)
{
    const int lane = threadIdx.x & 63;
    const int wave = blockIdx.x * 4 + (threadIdx.x >> 6);
    const int i0   = wave * 4;

    // lanes 0..31: angle for (row=l>>3, wire=l&7); lanes 32..38: theta[8..14]/2
    const int l = lane & 31;
    double arg;
    if (lane & 32) {
        arg = 0.5 * (double)theta[8 + (l < 7 ? l : 0)];
    } else {
        float a = mi[(size_t)(i0 + (l >> 3)) * 8 + (l & 7)];
        arg = 0.5 * ((double)a + (double)theta[l & 7]);
    }
    double sd, cd;
    sincos(arg, &sd, &cd);

    const double c8v  = __shfl(cd, 32), s8v  = __shfl(sd, 32);
    const double c9v  = __shfl(cd, 33), s9v  = __shfl(sd, 33);
    const double c10v = __shfl(cd, 34), s10v = __shfl(sd, 34);
    const double c11v = __shfl(cd, 35), s11v = __shfl(sd, 35);
    const double c12v = __shfl(cd, 36), s12v = __shfl(sd, 36);
    const double c13v = __shfl(cd, 37), s13v = __shfl(sd, 37);
    const double c14v = __shfl(cd, 38), s14v = __shfl(sd, 38);

    #pragma unroll
    for (int r = 0; r < 4; ++r) {
        const double cw0 = __shfl(cd, r * 8 + 0), sw0 = __shfl(sd, r * 8 + 0);
        const double cw1 = __shfl(cd, r * 8 + 1), sw1 = __shfl(sd, r * 8 + 1);
        const double cw2 = __shfl(cd, r * 8 + 2), sw2 = __shfl(sd, r * 8 + 2);
        const double cw3 = __shfl(cd, r * 8 + 3), sw3 = __shfl(sd, r * 8 + 3);
        const double cw4 = __shfl(cd, r * 8 + 4), sw4 = __shfl(sd, r * 8 + 4);
        const double cw5 = __shfl(cd, r * 8 + 5), sw5 = __shfl(sd, r * 8 + 5);
        const double cw6 = __shfl(cd, r * 8 + 6), sw6 = __shfl(sd, r * 8 + 6);
        const double cw7 = __shfl(cd, r * 8 + 7), sw7 = __shfl(sd, r * 8 + 7);

        // product state (first RY layer with theta[0..7] folded in)
        double base = (lane & 1)  ? sw0 : cw0;
        base *=       (lane & 2)  ? sw1 : cw1;
        base *=       (lane & 4)  ? sw2 : cw2;
        base *=       (lane & 8)  ? sw3 : cw3;
        base *=       (lane & 16) ? sw4 : cw4;
        base *=       (lane & 32) ? sw5 : cw5;

        double amp[4];
        amp[0] = base * cw6 * cw7;
        amp[1] = base * sw6 * cw7;
        amp[2] = base * cw6 * sw7;
        amp[3] = base * sw6 * sw7;

        cnot_ll(amp, lane, 1, 2);    // CNOT(0,1)
        cnot_ll(amp, lane, 8, 4);    // CNOT(3,2)
        cnot_ll(amp, lane, 16, 32);  // CNOT(4,5)
        { double tmp = amp[2]; amp[2] = amp[3]; amp[3] = tmp; } // CNOT(7,6)
        ry_lane(amp, lane, 2,  c8v,  s8v);   // RY(th8,  w1)
        ry_lane(amp, lane, 4,  c9v,  s9v);   // RY(th9,  w2)
        cnot_ll(amp, lane, 2, 4);    // CNOT(1,2)
        ry_lane(amp, lane, 32, c10v, s10v);  // RY(th10, w5)
        { // RY(th11, w6): register-bit pairs (0,1),(2,3)
            double n0 = fma(c11v, amp[0], -s11v * amp[1]);
            double n1 = fma(s11v, amp[0],  c11v * amp[1]);
            double n2 = fma(c11v, amp[2], -s11v * amp[3]);
            double n3 = fma(s11v, amp[2],  c11v * amp[3]);
            amp[0] = n0; amp[1] = n1; amp[2] = n2; amp[3] = n3;
        }
        // CNOT(6,5): control reg-bit0 -> regs 1,3 swap lane bit5
        amp[1] = __shfl_xor(amp[1], 32);
        amp[3] = __shfl_xor(amp[3], 32);
        ry_lane(amp, lane, 4,  c12v, s12v);  // RY(th12, w2)
        ry_lane(amp, lane, 32, c13v, s13v);  // RY(th13, w5)
        cnot_ll(amp, lane, 4, 32);   // CNOT(2,5)
        ry_lane(amp, lane, 32, c14v, s14v);  // RY(th14, w5)

        // z = sum amp^2 * (1 - 2*bit5)
        double m = amp[0] * amp[0];
        m = fma(amp[1], amp[1], m);
        m = fma(amp[2], amp[2], m);
        m = fma(amp[3], amp[3], m);
        double zp = (lane & 32) ? -m : m;
        zp += __shfl_xor(zp, 1);
        zp += __shfl_xor(zp, 2);
        zp += __shfl_xor(zp, 4);
        zp += __shfl_xor(zp, 8);
        zp += __shfl_xor(zp, 16);
        zp += __shfl_xor(zp, 32);
        if (lane == 0) out[i0 + r] = (float)(0.5 - 0.5 * zp);
    }
}

extern "C" void kernel_launch(void* const* d_in, const int* in_sizes, int n_in,
                              void* d_out, int out_size, void* d_ws, size_t ws_size,
                              hipStream_t stream) {
    const float* X  = (const float*)d_in[0];
    const float* e  = (const float*)d_in[1];
    const float* Ri = (const float*)d_in[2];
    const float* Ro = (const float*)d_in[3];
    const float* th = (const float*)d_in[4];
    float* out = (float*)d_out;

    float* bo = (float*)d_ws;                 // 16384*8 f32 = 512 KB
    float* mi = bo + (size_t)N_E * 8;         // 8192*8  f32 = 256 KB

    kbo  <<<N_E / 64,           64,  0, stream>>>(Ro, X, bo);
    kmi  <<<(N_ROWS * 8) / 256, 256, 0, stream>>>(Ri, e, bo, mi);
    kcirc<<<N_ROWS / 16,        256, 0, stream>>>(mi, th, out);
}

// Round 20
// 248.192 us; speedup vs baseline: 21.2942x; 21.2942x over previous
//
#include <hip/hip_runtime.h>

namespace {
constexpr int N_ROWS = 8192;
constexpr int N_E    = 16384;
constexpr int D      = 256;
constexpr int KC     = 512;                  // BLIS/AOCL kc (exact: 16 and 32 panels)
constexpr int NPB    = N_ROWS / KC;          // 16 panels for kbo
constexpr int NPM    = N_E    / KC;          // 32 panels for kmi
}

// kbo_panel: partial_bo[p][j][k] = panel-p chain of bo[j][k].
// Within panel: loc[k]=0; ascending n: loc[k]=fmaf(Ro[n][j],X[n][k],loc[k]).
// Identical FP sequence to the verified R19 kernel; panels parallelized.
__global__ __launch_bounds__(256) void kbo_panel(
    const float* __restrict__ Ro, const float* __restrict__ X,
    float* __restrict__ partial)
{
    __shared__ float xs[KC][8];
    const int t  = threadIdx.x;
    const int p  = blockIdx.y;
    const int n0 = p * KC;
    const int j  = blockIdx.x * 256 + t;

    for (int r = t; r < KC; r += 256) {      // stage X[n0..n0+512][0..8]
        const float4* xp = (const float4*)(X + (size_t)(n0 + r) * D);
        float4 a = xp[0], b = xp[1];
        *(float4*)&xs[r][0] = a;
        *(float4*)&xs[r][4] = b;
    }
    __syncthreads();

    float loc[8];
    #pragma unroll
    for (int k = 0; k < 8; ++k) loc[k] = 0.f;

    const float* rp = Ro + (size_t)n0 * N_E + j;
    for (int tt = 0; tt < KC; tt += 8) {
        float rv[8];
        #pragma unroll
        for (int u = 0; u < 8; ++u)
            rv[u] = rp[(size_t)(tt + u) * N_E];
        #pragma unroll
        for (int u = 0; u < 8; ++u) {
            #pragma unroll
            for (int k = 0; k < 8; ++k)
                loc[k] = fmaf(rv[u], xs[tt + u][k], loc[k]);
        }
    }

    float* pb = partial + ((size_t)p * N_E + j) * 8;
    *(float4*)(pb + 0) = make_float4(loc[0], loc[1], loc[2], loc[3]);
    *(float4*)(pb + 4) = make_float4(loc[4], loc[5], loc[6], loc[7]);
}

// kbo_combine: bo[j][k] = ((0 + loc_p0) + loc_p1) + ... ascending panels —
// exactly R19's per-panel C += loc sequence.
__global__ __launch_bounds__(256) void kbo_combine(
    const float* __restrict__ partial, float* __restrict__ bo)
{
    const int tid = blockIdx.x * 256 + threadIdx.x;   // (j,k) flat
    float C = 0.f;
    #pragma unroll
    for (int p = 0; p < NPB; ++p)
        C += partial[(size_t)p * N_E * 8 + tid];
    bo[tid] = C;
}

// kmi_panel: partial_mi[p][i][k] = panel-p chain of mi[i][k].
// Within panel: loc=0; ascending j: w=__fmul_rn(Ri,e); loc=fmaf(w,bo[j][k],loc).
__global__ __launch_bounds__(256) void kmi_panel(
    const float* __restrict__ Ri, const float* __restrict__ e,
    const float* __restrict__ bo, float* __restrict__ partial)
{
    __shared__ float bos[KC][8];
    __shared__ float es[KC];
    const int t  = threadIdx.x;
    const int p  = blockIdx.y;
    const int j0 = p * KC;

    {   // stage bo[j0..j0+512][0..8] (4096 f32) and e[j0..j0+512]
        const float4* src = (const float4*)(bo + (size_t)j0 * 8);
        float4* dst = (float4*)&bos[0][0];
        for (int q = t; q < KC * 2; q += 256) dst[q] = src[q];
        const float4* esrc = (const float4*)(e + j0);
        if (t < KC / 4) ((float4*)es)[t] = esrc[t];
    }
    __syncthreads();

    const int i = blockIdx.x * 256 + t;
    const float* rrow = Ri + (size_t)i * N_E + j0;

    float loc[8];
    #pragma unroll
    for (int k = 0; k < 8; ++k) loc[k] = 0.f;

    for (int tt = 0; tt < KC; tt += 16) {
        float4 r0 = *(const float4*)(rrow + tt + 0);
        float4 r1 = *(const float4*)(rrow + tt + 4);
        float4 r2 = *(const float4*)(rrow + tt + 8);
        float4 r3 = *(const float4*)(rrow + tt + 12);
        const float rv[16] = {r0.x, r0.y, r0.z, r0.w, r1.x, r1.y, r1.z, r1.w,
                              r2.x, r2.y, r2.z, r2.w, r3.x, r3.y, r3.z, r3.w};
        #pragma unroll
        for (int q = 0; q < 16; ++q) {
            const int jj = tt + q;
            const float w = __fmul_rn(rv[q], es[jj]);
            #pragma unroll
            for (int k = 0; k < 8; ++k)
                loc[k] = fmaf(w, bos[jj][k], loc[k]);
        }
    }

    float* pb = partial + ((size_t)p * N_ROWS + i) * 8;
    *(float4*)(pb + 0) = make_float4(loc[0], loc[1], loc[2], loc[3]);
    *(float4*)(pb + 4) = make_float4(loc[4], loc[5], loc[6], loc[7]);
}

// kmi_combine: mi[i][k] = ascending-panel sequential adds from zero.
__global__ __launch_bounds__(256) void kmi_combine(
    const float* __restrict__ partial, float* __restrict__ mi)
{
    const int tid = blockIdx.x * 256 + threadIdx.x;   // (i,k) flat
    float C = 0.f;
    #pragma unroll
    for (int p = 0; p < NPM; ++p)
        C += partial[(size_t)p * N_ROWS * 8 + tid];
    mi[tid] = C;
}

// ---- circuit helpers (f64): amp index bits 0..5 = lane, bits 6..7 = reg ----
__device__ __forceinline__ void cnot_ll(double amp[4], int lane, int cmask, int tmask) {
    const bool c = (lane & cmask) != 0;
    #pragma unroll
    for (int r = 0; r < 4; ++r) {
        double p = __shfl_xor(amp[r], tmask);
        amp[r] = c ? p : amp[r];
    }
}
__device__ __forceinline__ void ry_lane(double amp[4], int lane, int bmask, double cc, double ss) {
    const bool b = (lane & bmask) != 0;
    #pragma unroll
    for (int r = 0; r < 4; ++r) {
        double p  = __shfl_xor(amp[r], bmask);
        double sp = ss * p;
        amp[r] = fma(cc, amp[r], b ? sp : -sp);
    }
}

// kcirc: quantum circuit (f64) from f32 mi angles, 4 rows per wave
__global__ __launch_bounds__(256) void kcirc(
    const float* __restrict__ mi, const float* __restrict__ theta,
    float* __restrict__ out)
{
    const int lane = threadIdx.x & 63;
    const int wave = blockIdx.x * 4 + (threadIdx.x >> 6);
    const int i0   = wave * 4;

    const int l = lane & 31;
    double arg;
    if (lane & 32) {
        arg = 0.5 * (double)theta[8 + (l < 7 ? l : 0)];
    } else {
        float a = mi[(size_t)(i0 + (l >> 3)) * 8 + (l & 7)];
        arg = 0.5 * ((double)a + (double)theta[l & 7]);
    }
    double sd, cd;
    sincos(arg, &sd, &cd);

    const double c8v  = __shfl(cd, 32), s8v  = __shfl(sd, 32);
    const double c9v  = __shfl(cd, 33), s9v  = __shfl(sd, 33);
    const double c10v = __shfl(cd, 34), s10v = __shfl(sd, 34);
    const double c11v = __shfl(cd, 35), s11v = __shfl(sd, 35);
    const double c12v = __shfl(cd, 36), s12v = __shfl(sd, 36);
    const double c13v = __shfl(cd, 37), s13v = __shfl(sd, 37);
    const double c14v = __shfl(cd, 38), s14v = __shfl(sd, 38);

    #pragma unroll
    for (int r = 0; r < 4; ++r) {
        const double cw0 = __shfl(cd, r * 8 + 0), sw0 = __shfl(sd, r * 8 + 0);
        const double cw1 = __shfl(cd, r * 8 + 1), sw1 = __shfl(sd, r * 8 + 1);
        const double cw2 = __shfl(cd, r * 8 + 2), sw2 = __shfl(sd, r * 8 + 2);
        const double cw3 = __shfl(cd, r * 8 + 3), sw3 = __shfl(sd, r * 8 + 3);
        const double cw4 = __shfl(cd, r * 8 + 4), sw4 = __shfl(sd, r * 8 + 4);
        const double cw5 = __shfl(cd, r * 8 + 5), sw5 = __shfl(sd, r * 8 + 5);
        const double cw6 = __shfl(cd, r * 8 + 6), sw6 = __shfl(sd, r * 8 + 6);
        const double cw7 = __shfl(cd, r * 8 + 7), sw7 = __shfl(sd, r * 8 + 7);

        double base = (lane & 1)  ? sw0 : cw0;
        base *=       (lane & 2)  ? sw1 : cw1;
        base *=       (lane & 4)  ? sw2 : cw2;
        base *=       (lane & 8)  ? sw3 : cw3;
        base *=       (lane & 16) ? sw4 : cw4;
        base *=       (lane & 32) ? sw5 : cw5;

        double amp[4];
        amp[0] = base * cw6 * cw7;
        amp[1] = base * sw6 * cw7;
        amp[2] = base * cw6 * sw7;
        amp[3] = base * sw6 * sw7;

        cnot_ll(amp, lane, 1, 2);    // CNOT(0,1)
        cnot_ll(amp, lane, 8, 4);    // CNOT(3,2)
        cnot_ll(amp, lane, 16, 32);  // CNOT(4,5)
        { double tmp = amp[2]; amp[2] = amp[3]; amp[3] = tmp; } // CNOT(7,6)
        ry_lane(amp, lane, 2,  c8v,  s8v);   // RY(th8,  w1)
        ry_lane(amp, lane, 4,  c9v,  s9v);   // RY(th9,  w2)
        cnot_ll(amp, lane, 2, 4);    // CNOT(1,2)
        ry_lane(amp, lane, 32, c10v, s10v);  // RY(th10, w5)
        {
            double n0 = fma(c11v, amp[0], -s11v * amp[1]);
            double n1 = fma(s11v, amp[0],  c11v * amp[1]);
            double n2 = fma(c11v, amp[2], -s11v * amp[3]);
            double n3 = fma(s11v, amp[2],  c11v * amp[3]);
            amp[0] = n0; amp[1] = n1; amp[2] = n2; amp[3] = n3;
        }
        amp[1] = __shfl_xor(amp[1], 32);     // CNOT(6,5)
        amp[3] = __shfl_xor(amp[3], 32);
        ry_lane(amp, lane, 4,  c12v, s12v);  // RY(th12, w2)
        ry_lane(amp, lane, 32, c13v, s13v);  // RY(th13, w5)
        cnot_ll(amp, lane, 4, 32);   // CNOT(2,5)
        ry_lane(amp, lane, 32, c14v, s14v);  // RY(th14, w5)

        double m = amp[0] * amp[0];
        m = fma(amp[1], amp[1], m);
        m = fma(amp[2], amp[2], m);
        m = fma(amp[3], amp[3], m);
        double zp = (lane & 32) ? -m : m;
        zp += __shfl_xor(zp, 1);
        zp += __shfl_xor(zp, 2);
        zp += __shfl_xor(zp, 4);
        zp += __shfl_xor(zp, 8);
        zp += __shfl_xor(zp, 16);
        zp += __shfl_xor(zp, 32);
        if (lane == 0) out[i0 + r] = (float)(0.5 - 0.5 * zp);
    }
}

extern "C" void kernel_launch(void* const* d_in, const int* in_sizes, int n_in,
                              void* d_out, int out_size, void* d_ws, size_t ws_size,
                              hipStream_t stream) {
    const float* X  = (const float*)d_in[0];
    const float* e  = (const float*)d_in[1];
    const float* Ri = (const float*)d_in[2];
    const float* Ro = (const float*)d_in[3];
    const float* th = (const float*)d_in[4];
    float* out = (float*)d_out;

    float* bo  = (float*)d_ws;                       // 131072 f32 = 512 KB
    float* mi  = bo  + (size_t)N_E * 8;              //  65536 f32 = 256 KB
    float* pbo = mi  + (size_t)N_ROWS * 8;           // 16*131072 f32 = 8 MB
    float* pmi = pbo + (size_t)NPB * N_E * 8;        // 32*65536  f32 = 8 MB

    kbo_panel  <<<dim3(N_E / 256, NPB),    256, 0, stream>>>(Ro, X, pbo);
    kbo_combine<<<(N_E * 8) / 256,         256, 0, stream>>>(pbo, bo);
    kmi_panel  <<<dim3(N_ROWS / 256, NPM), 256, 0, stream>>>(Ri, e, bo, pmi);
    kmi_combine<<<(N_ROWS * 8) / 256,      256, 0, stream>>>(pmi, mi);
    kcirc      <<<N_ROWS / 16,             256, 0, stream>>>(mi, th, out);
}